// Round 1
// baseline (538.704 us; speedup 1.0000x reference)
//
#include <hip/hip_runtime.h>
#include <hip/hip_bf16.h>
#include <cstdint>
#include <cstddef>

// Problem constants (from reference): B=16, H=32, KVH=8, D=128, CACHE=4096
#define BATCH 16
#define HQ 32
#define KVHN 8
#define NREP 4
#define DIM 128
#define CACHE_LEN 4096
#define STATE_POS 128         // cached positions per partial state (one wave)
#define NSTATE (CACHE_LEN / STATE_POS)   // 32

__device__ __forceinline__ float half_reduce_sum(float v) {
    // reduce across the 32 lanes of this half-wave (xor masks stay within half)
    #pragma unroll
    for (int mask = 16; mask; mask >>= 1) v += __shfl_xor(v, mask, 64);
    return v;
}

// ---------------------------------------------------------------------------
// Kernel 1: per-(b,kvh,state) partial flash-decode over 128 cached positions.
// One wave (64 threads). Lane layout: half = lane>>5 picks position parity,
// hl = lane&31 picks dim slice d = 4*hl .. 4*hl+3 (int4 = 16B/lane).
// Wave loads 2 consecutive K rows (1 KiB contiguous) per iteration.
// ---------------------------------------------------------------------------
__global__ void attn_partial(
    const float* __restrict__ xq,
    const float* __restrict__ fcos,
    const float* __restrict__ fsin,
    const float* __restrict__ k_scaler,
    const float* __restrict__ v_scaler,
    const int*   __restrict__ cache_k,
    const int*   __restrict__ cache_v,
    const int*   __restrict__ input_pos,
    float* __restrict__ ws_acc,   // [B][KVH][NSTATE][4][DIM]
    float* __restrict__ ws_ml)    // [B][KVH][NSTATE][4][2]  (m,l)
{
    const int state = blockIdx.x;
    const int kvh   = blockIdx.y;
    const int b     = blockIdx.z;
    const int pos   = input_pos[b];          // cached positions are s < pos
    const int start = state * STATE_POS;
    if (start >= pos) return;                // state empty -> combine skips it

    const int lane = threadIdx.x;            // 0..63
    const int half = lane >> 5;
    const int hl   = lane & 31;
    const int d0   = hl * 4;

    // RoPE'd q fragment for this lane's 4 dims (pairs are self-contained).
    float q[4][4];
    {
        const float2 c2 = *(const float2*)(fcos + b * 64 + 2 * hl);
        const float2 s2 = *(const float2*)(fsin + b * 64 + 2 * hl);
        #pragma unroll
        for (int r = 0; r < 4; ++r) {
            const float4 x = *(const float4*)(xq + ((size_t)(b * HQ + kvh * NREP + r)) * DIM + d0);
            q[r][0] = x.x * c2.x - x.y * s2.x;
            q[r][1] = x.x * s2.x + x.y * c2.x;
            q[r][2] = x.z * c2.y - x.w * s2.y;
            q[r][3] = x.z * s2.y + x.w * c2.y;
        }
    }

    const int bk = b * KVHN + kvh;
    const int*   __restrict__ kb = cache_k + (size_t)bk * CACHE_LEN * DIM;
    const int*   __restrict__ vb = cache_v + (size_t)bk * CACHE_LEN * DIM;
    const float* __restrict__ ks = k_scaler + (size_t)bk * CACHE_LEN;
    const float* __restrict__ vs = v_scaler + (size_t)bk * CACHE_LEN;

    float m[4] = {-1e30f, -1e30f, -1e30f, -1e30f};
    float l[4] = {0.f, 0.f, 0.f, 0.f};
    float acc[4][4] = {};

    const int send = min(start + STATE_POS, pos);
    const float rsD = 0.088388347648318447f;   // 1/sqrt(128)

    for (int i = 0; ; ++i) {
        const int slo = start + 2 * i;
        if (slo >= send) break;                // wave-uniform
        const int s = slo + half;              // <= 4095 always (addr safe)
        const bool valid = s < send;

        const int4 kk = *(const int4*)(kb + (size_t)s * DIM + d0);
        const float k0 = (float)kk.x, k1 = (float)kk.y, k2 = (float)kk.z, k3 = (float)kk.w;
        float p[4];
        #pragma unroll
        for (int r = 0; r < 4; ++r)
            p[r] = q[r][0] * k0 + q[r][1] * k1 + q[r][2] * k2 + q[r][3] * k3;
        #pragma unroll
        for (int mask = 16; mask; mask >>= 1) {
            #pragma unroll
            for (int r = 0; r < 4; ++r) p[r] += __shfl_xor(p[r], mask, 64);
        }

        const float scale = ks[s] * rsD;
        const int4 vv = *(const int4*)(vb + (size_t)s * DIM + d0);
        const float v0 = (float)vv.x, v1 = (float)vv.y, v2 = (float)vv.z, v3 = (float)vv.w;
        const float vsc = vs[s];

        #pragma unroll
        for (int r = 0; r < 4; ++r) {
            float sc = p[r] * scale;
            if (!valid) sc = -1e30f;
            const float mn = fmaxf(m[r], sc);
            const float alpha = __expf(m[r] - mn);   // m==-1e30 & mn finite -> 0
            float pr = __expf(sc - mn);
            if (!valid) pr = 0.f;                    // guard exp(0)=1 at floor
            m[r] = mn;
            l[r] = l[r] * alpha + pr;
            const float pv = pr * vsc;
            acc[r][0] = acc[r][0] * alpha + pv * v0;
            acc[r][1] = acc[r][1] * alpha + pv * v1;
            acc[r][2] = acc[r][2] * alpha + pv * v2;
            acc[r][3] = acc[r][3] * alpha + pv * v3;
        }
    }

    // merge the two half-wave softmax states
    float4 A[4]; float Mv[4], Lv[4];
    #pragma unroll
    for (int r = 0; r < 4; ++r) {
        const float mo = __shfl_xor(m[r], 32, 64);
        const float lo = __shfl_xor(l[r], 32, 64);
        float ao0 = __shfl_xor(acc[r][0], 32, 64);
        float ao1 = __shfl_xor(acc[r][1], 32, 64);
        float ao2 = __shfl_xor(acc[r][2], 32, 64);
        float ao3 = __shfl_xor(acc[r][3], 32, 64);
        const float M  = fmaxf(m[r], mo);            // finite: lower half has >=1 valid pos
        const float a1 = __expf(m[r] - M);
        const float a2 = __expf(mo   - M);
        Mv[r] = M;
        Lv[r] = l[r] * a1 + lo * a2;
        A[r].x = acc[r][0] * a1 + ao0 * a2;
        A[r].y = acc[r][1] * a1 + ao1 * a2;
        A[r].z = acc[r][2] * a1 + ao2 * a2;
        A[r].w = acc[r][3] * a1 + ao3 * a2;
    }

    if (half == 0) {
        float* abase = ws_acc + (((size_t)bk * NSTATE + state) * 4) * DIM;
        #pragma unroll
        for (int r = 0; r < 4; ++r)
            *(float4*)(abase + r * DIM + d0) = A[r];
        if (lane == 0) {
            float* mlb = ws_ml + ((size_t)bk * NSTATE + state) * 8;
            #pragma unroll
            for (int r = 0; r < 4; ++r) { mlb[2 * r] = Mv[r]; mlb[2 * r + 1] = Lv[r]; }
        }
    }
}

// ---------------------------------------------------------------------------
// Kernel 2: per-(b,kvh) combine. Recomputes RoPE q, quantizes the new token
// (exactly replicating the reference: max|x|/127+1e-8, round-half-even, clip),
// adds it as one extra softmax state, merges all partials, writes f32 out.
// ---------------------------------------------------------------------------
__global__ __launch_bounds__(256) void attn_combine(
    const float* __restrict__ xq,
    const float* __restrict__ xk,
    const float* __restrict__ xv,
    const float* __restrict__ fcos,
    const float* __restrict__ fsin,
    const int*   __restrict__ input_pos,
    const float* __restrict__ ws_acc,
    const float* __restrict__ ws_ml,
    float* __restrict__ out)
{
    const int bk  = blockIdx.x;
    const int b   = bk >> 3;
    const int kvh = bk & 7;
    const int pos = input_pos[b];
    const int nst = min(NSTATE, (pos + STATE_POS - 1) / STATE_POS);

    const int t    = threadIdx.x;
    const int lane = t & 63;
    const int w    = t >> 6;          // wave id 0..3

    __shared__ float sq[4][DIM];      // RoPE'd q
    __shared__ float skq[DIM];        // rope'd k, then quantized k (int-valued)
    __shared__ float svd[DIM];        // dequantized new v  (v_s * v_q)
    __shared__ float sml[NSTATE][8];  // staged (m,l) per state per head
    __shared__ float ssc[4];          // new-token score per head
    __shared__ float sks, svs;

    const float rsD = 0.088388347648318447f;

    // q RoPE: thread (w=r, lane=p) handles pair p of head r
    {
        const float c  = fcos[b * 64 + lane];
        const float s  = fsin[b * 64 + lane];
        const size_t qb = ((size_t)(b * HQ + kvh * NREP + w)) * DIM;
        const float xe = xq[qb + 2 * lane];
        const float xo = xq[qb + 2 * lane + 1];
        sq[w][2 * lane]     = xe * c - xo * s;
        sq[w][2 * lane + 1] = xe * s + xo * c;
    }
    // k RoPE (wave 0)
    if (w == 0) {
        const float c  = fcos[b * 64 + lane];
        const float s  = fsin[b * 64 + lane];
        const size_t kbb = ((size_t)(b * KVHN + kvh)) * DIM;
        const float xe = xk[kbb + 2 * lane];
        const float xo = xk[kbb + 2 * lane + 1];
        skq[2 * lane]     = xe * c - xo * s;
        skq[2 * lane + 1] = xe * s + xo * c;
    }
    // stage (m,l): only first nst*8 floats are valid in ws
    if (t < nst * 8) sml[t >> 3][t & 7] = ws_ml[(size_t)bk * NSTATE * 8 + t];
    __syncthreads();

    // scalers: k_s from rope'd k (wave 0), v_s from xv (wave 1)
    if (w == 0) {
        float a = fmaxf(fabsf(skq[lane]), fabsf(skq[64 + lane]));
        #pragma unroll
        for (int mask = 32; mask; mask >>= 1) a = fmaxf(a, __shfl_xor(a, mask, 64));
        if (lane == 0) sks = a / 127.0f + 1e-8f;
    } else if (w == 1) {
        const size_t vbb = ((size_t)(b * KVHN + kvh)) * DIM;
        float a = fmaxf(fabsf(xv[vbb + lane]), fabsf(xv[vbb + 64 + lane]));
        #pragma unroll
        for (int mask = 32; mask; mask >>= 1) a = fmaxf(a, __shfl_xor(a, mask, 64));
        if (lane == 0) svs = a / 127.0f + 1e-8f;
    }
    __syncthreads();

    // quantize k, dequantized new v
    if (t < DIM) {
        skq[t] = fminf(fmaxf(rintf(skq[t] / sks), -127.f), 127.f);
    } else {
        const int d = t - DIM;
        const size_t vbb = ((size_t)(b * KVHN + kvh)) * DIM;
        const float vq = fminf(fmaxf(rintf(xv[vbb + d] / svs), -127.f), 127.f);
        svd[d] = vq * svs;
    }
    __syncthreads();

    // new-token score for head w
    {
        float sum = sq[w][lane] * skq[lane] + sq[w][64 + lane] * skq[64 + lane];
        #pragma unroll
        for (int mask = 32; mask; mask >>= 1) sum += __shfl_xor(sum, mask, 64);
        if (lane == 0) ssc[w] = sum * rsD * sks;
    }
    __syncthreads();

    // final combine: thread (w=r, lane=db) handles dims db and db+64
    const int r  = w;
    const int db = lane;
    float M = ssc[r];
    for (int s2 = 0; s2 < nst; ++s2) M = fmaxf(M, sml[s2][2 * r]);
    const float pn = __expf(ssc[r] - M);
    float L  = pn;
    float o0 = pn * svd[db];
    float o1 = pn * svd[db + 64];
    const float* ab = ws_acc + (size_t)bk * NSTATE * 4 * DIM;
    for (int s2 = 0; s2 < nst; ++s2) {
        const float al = __expf(sml[s2][2 * r] - M);
        L  += sml[s2][2 * r + 1] * al;
        o0 += ab[((size_t)(s2 * 4 + r)) * DIM + db]      * al;
        o1 += ab[((size_t)(s2 * 4 + r)) * DIM + db + 64] * al;
    }
    const float invL = 1.0f / L;
    float* ob = out + ((size_t)(b * HQ + kvh * NREP + r)) * DIM;
    ob[db]      = o0 * invL;
    ob[db + 64] = o1 * invL;
}

extern "C" void kernel_launch(void* const* d_in, const int* in_sizes, int n_in,
                              void* d_out, int out_size, void* d_ws, size_t ws_size,
                              hipStream_t stream)
{
    const float* xq        = (const float*)d_in[0];
    const float* xk        = (const float*)d_in[1];
    const float* xv        = (const float*)d_in[2];
    const float* fcos      = (const float*)d_in[3];
    const float* fsin      = (const float*)d_in[4];
    const float* k_scaler  = (const float*)d_in[5];
    const float* v_scaler  = (const float*)d_in[6];
    const int*   cache_k   = (const int*)d_in[7];
    const int*   cache_v   = (const int*)d_in[8];
    const int*   input_pos = (const int*)d_in[9];
    float* out = (float*)d_out;

    float* ws_acc = (float*)d_ws;                                   // 8 MiB
    float* ws_ml  = ws_acc + (size_t)BATCH * KVHN * NSTATE * 4 * DIM; // +128 KiB

    dim3 g1(NSTATE, KVHN, BATCH);
    attn_partial<<<g1, 64, 0, stream>>>(xq, fcos, fsin, k_scaler, v_scaler,
                                        cache_k, cache_v, input_pos, ws_acc, ws_ml);
    attn_combine<<<BATCH * KVHN, 256, 0, stream>>>(xq, xk, xv, fcos, fsin,
                                                   input_pos, ws_acc, ws_ml, out);
}

// Round 2
// 503.688 us; speedup vs baseline: 1.0695x; 1.0695x over previous
//
#include <hip/hip_runtime.h>
#include <hip/hip_bf16.h>
#include <cstdint>
#include <cstddef>

// Problem constants (from reference): B=16, H=32, KVH=8, D=128, CACHE=4096
#define BATCH 16
#define HQ 32
#define KVHN 8
#define NREP 4
#define DIM 128
#define CACHE_LEN 4096
#define STATE_POS 128                    // cached positions per partial state (one wave)
#define NSTATE (CACHE_LEN / STATE_POS)   // 32

// ---------------------------------------------------------------------------
// Kernel 1: per-(b,kvh,state) partial flash-decode over 128 cached positions.
// One wave (64 threads) = 4 groups of 16 lanes. Group g handles position
// s = start + i*4 + g at iteration i; lane sl (0..15) owns dims 8*sl..8*sl+7
// (2 contiguous int4 loads = 32B/lane). Two-pass softmax:
//   K-pass: scores -> LDS (float4 = 4 heads per position), running max in regs
//   wave max via 2 shuffles; V-pass: exp + plain accumulate (no rescaling,
//   no loop-carried dependencies -> full software pipelining of loads).
// Masked tail positions get score -1e30 -> exp()==0; loads stay in-bounds.
// ---------------------------------------------------------------------------
__global__ __launch_bounds__(64) void attn_partial(
    const float* __restrict__ xq,
    const float* __restrict__ fcos,
    const float* __restrict__ fsin,
    const float* __restrict__ k_scaler,
    const float* __restrict__ v_scaler,
    const int*   __restrict__ cache_k,
    const int*   __restrict__ cache_v,
    const int*   __restrict__ input_pos,
    float* __restrict__ ws_acc,   // [B][KVH][NSTATE][4][DIM]
    float* __restrict__ ws_ml)    // [B][KVH][NSTATE][4][2]  (m,l)
{
    const int state = blockIdx.x;
    const int kvh   = blockIdx.y;
    const int b     = blockIdx.z;
    const int pos   = input_pos[b];          // cached positions are s < pos
    const int start = state * STATE_POS;
    if (start >= pos) return;                // state empty -> combine skips it

    const int lane = threadIdx.x;            // 0..63
    const int g    = lane >> 4;              // position group 0..3
    const int sl   = lane & 15;              // dim slice
    const int d0   = sl * 8;

    const int send = min(start + STATE_POS, pos);
    const float rsD = 0.088388347648318447f; // 1/sqrt(128)

    // RoPE'd q fragment for this lane's 8 dims, pre-scaled by 1/sqrt(D).
    float q[4][8];
    {
        float4 c4 = *(const float4*)(fcos + b * 64 + sl * 4);
        float4 s4 = *(const float4*)(fsin + b * 64 + sl * 4);
        c4.x *= rsD; c4.y *= rsD; c4.z *= rsD; c4.w *= rsD;
        s4.x *= rsD; s4.y *= rsD; s4.z *= rsD; s4.w *= rsD;
        #pragma unroll
        for (int r = 0; r < 4; ++r) {
            const float* qp = xq + ((size_t)(b * HQ + kvh * NREP + r)) * DIM + d0;
            const float4 x0 = *(const float4*)qp;
            const float4 x1 = *(const float4*)(qp + 4);
            q[r][0] = x0.x * c4.x - x0.y * s4.x;
            q[r][1] = x0.x * s4.x + x0.y * c4.x;
            q[r][2] = x0.z * c4.y - x0.w * s4.y;
            q[r][3] = x0.z * s4.y + x0.w * c4.y;
            q[r][4] = x1.x * c4.z - x1.y * s4.z;
            q[r][5] = x1.x * s4.z + x1.y * c4.z;
            q[r][6] = x1.z * c4.w - x1.w * s4.w;
            q[r][7] = x1.z * s4.w + x1.w * c4.w;
        }
    }

    const int bk = b * KVHN + kvh;
    const int*   __restrict__ kb = cache_k + (size_t)bk * CACHE_LEN * DIM;
    const int*   __restrict__ vb = cache_v + (size_t)bk * CACHE_LEN * DIM;
    const float* __restrict__ ks = k_scaler + (size_t)bk * CACHE_LEN;
    const float* __restrict__ vs = v_scaler + (size_t)bk * CACHE_LEN;

    __shared__ float4 ssc4[STATE_POS];       // per-position scores, 4 heads

    float mloc[4] = {-1e30f, -1e30f, -1e30f, -1e30f};

    // ---------------- K pass: scores -> LDS, running max ----------------
    #pragma unroll 4
    for (int i = 0; i < STATE_POS / 4; ++i) {
        const int s = start + i * 4 + g;     // always <= 4095 (addr safe)
        const int* kp = kb + (size_t)s * DIM + d0;
        const int4 kk0 = *(const int4*)kp;
        const int4 kk1 = *(const int4*)(kp + 4);
        const float k0 = (float)kk0.x, k1 = (float)kk0.y, k2 = (float)kk0.z, k3 = (float)kk0.w;
        const float k4 = (float)kk1.x, k5 = (float)kk1.y, k6 = (float)kk1.z, k7 = (float)kk1.w;
        float p[4];
        #pragma unroll
        for (int r = 0; r < 4; ++r) {
            p[r] = q[r][0] * k0 + q[r][1] * k1 + q[r][2] * k2 + q[r][3] * k3
                 + q[r][4] * k4 + q[r][5] * k5 + q[r][6] * k6 + q[r][7] * k7;
        }
        #pragma unroll
        for (int mask = 1; mask <= 8; mask <<= 1) {
            #pragma unroll
            for (int r = 0; r < 4; ++r) p[r] += __shfl_xor(p[r], mask, 64);
        }
        const float scale = ks[s];
        const bool valid = s < send;
        float4 sc;
        sc.x = valid ? p[0] * scale : -1e30f;
        sc.y = valid ? p[1] * scale : -1e30f;
        sc.z = valid ? p[2] * scale : -1e30f;
        sc.w = valid ? p[3] * scale : -1e30f;
        mloc[0] = fmaxf(mloc[0], sc.x);
        mloc[1] = fmaxf(mloc[1], sc.y);
        mloc[2] = fmaxf(mloc[2], sc.z);
        mloc[3] = fmaxf(mloc[3], sc.w);
        if (sl == 0) ssc4[i * 4 + g] = sc;
    }

    // wave-wide max per head (groups differ only across lane bits 4,5)
    #pragma unroll
    for (int r = 0; r < 4; ++r) {
        mloc[r] = fmaxf(mloc[r], __shfl_xor(mloc[r], 16, 64));
        mloc[r] = fmaxf(mloc[r], __shfl_xor(mloc[r], 32, 64));
    }
    __syncthreads();

    // ---------------- V pass: exp + plain accumulate ----------------
    float l[4] = {0.f, 0.f, 0.f, 0.f};
    float acc[4][8] = {};
    #pragma unroll 4
    for (int i = 0; i < STATE_POS / 4; ++i) {
        const int s = start + i * 4 + g;
        const int* vp = vb + (size_t)s * DIM + d0;
        const int4 vv0 = *(const int4*)vp;
        const int4 vv1 = *(const int4*)(vp + 4);
        const float vsc = vs[s];
        const float4 sc = ssc4[i * 4 + g];   // broadcast within group
        const float v0 = (float)vv0.x, v1 = (float)vv0.y, v2 = (float)vv0.z, v3 = (float)vv0.w;
        const float v4 = (float)vv1.x, v5 = (float)vv1.y, v6 = (float)vv1.z, v7 = (float)vv1.w;
        const float scr[4] = {sc.x, sc.y, sc.z, sc.w};
        #pragma unroll
        for (int r = 0; r < 4; ++r) {
            const float pr = __expf(scr[r] - mloc[r]);  // invalid: exp(-1e30)=0
            l[r] += pr;
            const float pv = pr * vsc;
            acc[r][0] += pv * v0; acc[r][1] += pv * v1;
            acc[r][2] += pv * v2; acc[r][3] += pv * v3;
            acc[r][4] += pv * v4; acc[r][5] += pv * v5;
            acc[r][6] += pv * v6; acc[r][7] += pv * v7;
        }
    }

    // merge the 4 group states: plain sums (max was wave-uniform already)
    #pragma unroll
    for (int mask = 16; mask <= 32; mask <<= 1) {
        #pragma unroll
        for (int r = 0; r < 4; ++r) {
            l[r] += __shfl_xor(l[r], mask, 64);
            #pragma unroll
            for (int c = 0; c < 8; ++c) acc[r][c] += __shfl_xor(acc[r][c], mask, 64);
        }
    }

    if (g == 0) {                            // lanes 0..15 hold the totals
        float* abase = ws_acc + (((size_t)bk * NSTATE + state) * 4) * DIM;
        #pragma unroll
        for (int r = 0; r < 4; ++r) {
            float4 a0 = make_float4(acc[r][0], acc[r][1], acc[r][2], acc[r][3]);
            float4 a1 = make_float4(acc[r][4], acc[r][5], acc[r][6], acc[r][7]);
            *(float4*)(abase + r * DIM + d0)     = a0;
            *(float4*)(abase + r * DIM + d0 + 4) = a1;
        }
        if (sl == 0) {
            float* mlb = ws_ml + ((size_t)bk * NSTATE + state) * 8;
            #pragma unroll
            for (int r = 0; r < 4; ++r) { mlb[2 * r] = mloc[r]; mlb[2 * r + 1] = l[r]; }
        }
    }
}

// ---------------------------------------------------------------------------
// Kernel 2: per-(b,kvh) combine. Recomputes RoPE q, quantizes the new token
// (exactly replicating the reference: max|x|/127+1e-8, round-half-even, clip),
// adds it as one extra softmax state, merges all partials, writes f32 out.
// ---------------------------------------------------------------------------
__global__ __launch_bounds__(256) void attn_combine(
    const float* __restrict__ xq,
    const float* __restrict__ xk,
    const float* __restrict__ xv,
    const float* __restrict__ fcos,
    const float* __restrict__ fsin,
    const int*   __restrict__ input_pos,
    const float* __restrict__ ws_acc,
    const float* __restrict__ ws_ml,
    float* __restrict__ out)
{
    const int bk  = blockIdx.x;
    const int b   = bk >> 3;
    const int kvh = bk & 7;
    const int pos = input_pos[b];
    const int nst = min(NSTATE, (pos + STATE_POS - 1) / STATE_POS);

    const int t    = threadIdx.x;
    const int lane = t & 63;
    const int w    = t >> 6;          // wave id 0..3

    __shared__ float sq[4][DIM];      // RoPE'd q
    __shared__ float skq[DIM];        // rope'd k, then quantized k (int-valued)
    __shared__ float svd[DIM];        // dequantized new v  (v_s * v_q)
    __shared__ float sml[NSTATE][8];  // staged (m,l) per state per head
    __shared__ float ssc[4];          // new-token score per head
    __shared__ float sks, svs;

    const float rsD = 0.088388347648318447f;

    // q RoPE: thread (w=r, lane=p) handles pair p of head r
    {
        const float c  = fcos[b * 64 + lane];
        const float s  = fsin[b * 64 + lane];
        const size_t qb = ((size_t)(b * HQ + kvh * NREP + w)) * DIM;
        const float xe = xq[qb + 2 * lane];
        const float xo = xq[qb + 2 * lane + 1];
        sq[w][2 * lane]     = xe * c - xo * s;
        sq[w][2 * lane + 1] = xe * s + xo * c;
    }
    // k RoPE (wave 0)
    if (w == 0) {
        const float c  = fcos[b * 64 + lane];
        const float s  = fsin[b * 64 + lane];
        const size_t kbb = ((size_t)(b * KVHN + kvh)) * DIM;
        const float xe = xk[kbb + 2 * lane];
        const float xo = xk[kbb + 2 * lane + 1];
        skq[2 * lane]     = xe * c - xo * s;
        skq[2 * lane + 1] = xe * s + xo * c;
    }
    // stage (m,l): only first nst*8 floats are valid in ws
    if (t < nst * 8) sml[t >> 3][t & 7] = ws_ml[(size_t)bk * NSTATE * 8 + t];
    __syncthreads();

    // scalers: k_s from rope'd k (wave 0), v_s from xv (wave 1)
    if (w == 0) {
        float a = fmaxf(fabsf(skq[lane]), fabsf(skq[64 + lane]));
        #pragma unroll
        for (int mask = 32; mask; mask >>= 1) a = fmaxf(a, __shfl_xor(a, mask, 64));
        if (lane == 0) sks = a / 127.0f + 1e-8f;
    } else if (w == 1) {
        const size_t vbb = ((size_t)(b * KVHN + kvh)) * DIM;
        float a = fmaxf(fabsf(xv[vbb + lane]), fabsf(xv[vbb + 64 + lane]));
        #pragma unroll
        for (int mask = 32; mask; mask >>= 1) a = fmaxf(a, __shfl_xor(a, mask, 64));
        if (lane == 0) svs = a / 127.0f + 1e-8f;
    }
    __syncthreads();

    // quantize k, dequantized new v
    if (t < DIM) {
        skq[t] = fminf(fmaxf(rintf(skq[t] / sks), -127.f), 127.f);
    } else {
        const int d = t - DIM;
        const size_t vbb = ((size_t)(b * KVHN + kvh)) * DIM;
        const float vq = fminf(fmaxf(rintf(xv[vbb + d] / svs), -127.f), 127.f);
        svd[d] = vq * svs;
    }
    __syncthreads();

    // new-token score for head w
    {
        float sum = sq[w][lane] * skq[lane] + sq[w][64 + lane] * skq[64 + lane];
        #pragma unroll
        for (int mask = 32; mask; mask >>= 1) sum += __shfl_xor(sum, mask, 64);
        if (lane == 0) ssc[w] = sum * rsD * sks;
    }
    __syncthreads();

    // final combine: thread (w=r, lane=db) handles dims db and db+64
    const int r  = w;
    const int db = lane;
    float M = ssc[r];
    for (int s2 = 0; s2 < nst; ++s2) M = fmaxf(M, sml[s2][2 * r]);
    const float pn = __expf(ssc[r] - M);
    float L  = pn;
    float o0 = pn * svd[db];
    float o1 = pn * svd[db + 64];
    const float* ab = ws_acc + (size_t)bk * NSTATE * 4 * DIM;
    for (int s2 = 0; s2 < nst; ++s2) {
        const float al = __expf(sml[s2][2 * r] - M);
        L  += sml[s2][2 * r + 1] * al;
        o0 += ab[((size_t)(s2 * 4 + r)) * DIM + db]      * al;
        o1 += ab[((size_t)(s2 * 4 + r)) * DIM + db + 64] * al;
    }
    const float invL = 1.0f / L;
    float* ob = out + ((size_t)(b * HQ + kvh * NREP + r)) * DIM;
    ob[db]      = o0 * invL;
    ob[db + 64] = o1 * invL;
}

extern "C" void kernel_launch(void* const* d_in, const int* in_sizes, int n_in,
                              void* d_out, int out_size, void* d_ws, size_t ws_size,
                              hipStream_t stream)
{
    const float* xq        = (const float*)d_in[0];
    const float* xk        = (const float*)d_in[1];
    const float* xv        = (const float*)d_in[2];
    const float* fcos      = (const float*)d_in[3];
    const float* fsin      = (const float*)d_in[4];
    const float* k_scaler  = (const float*)d_in[5];
    const float* v_scaler  = (const float*)d_in[6];
    const int*   cache_k   = (const int*)d_in[7];
    const int*   cache_v   = (const int*)d_in[8];
    const int*   input_pos = (const int*)d_in[9];
    float* out = (float*)d_out;

    float* ws_acc = (float*)d_ws;                                     // 8 MiB
    float* ws_ml  = ws_acc + (size_t)BATCH * KVHN * NSTATE * 4 * DIM; // +128 KiB

    dim3 g1(NSTATE, KVHN, BATCH);
    attn_partial<<<g1, 64, 0, stream>>>(xq, fcos, fsin, k_scaler, v_scaler,
                                        cache_k, cache_v, input_pos, ws_acc, ws_ml);
    attn_combine<<<BATCH * KVHN, 256, 0, stream>>>(xq, xk, xv, fcos, fsin,
                                                   input_pos, ws_acc, ws_ml, out);
}